// Round 8
// baseline (602.820 us; speedup 1.0000x reference)
//
#include <hip/hip_runtime.h>
#include <hip/hip_bf16.h>
#include <math.h>
#include <stdint.h>

typedef __bf16 bf16_t;
typedef __bf16 bf16x2 __attribute__((ext_vector_type(2)));
typedef __bf16 bf16x4 __attribute__((ext_vector_type(4)));
typedef __bf16 bf16x8 __attribute__((ext_vector_type(8)));
typedef float  f32x4  __attribute__((ext_vector_type(4)));
typedef float  f32x16 __attribute__((ext_vector_type(16)));

#define NB   64
#define SEQ  2048
#define HD   128
#define BM   128        // fallback kernel q-tile
#define BMW  256        // ws kernel q-tile (8 waves x 32)
#define BN   64
#define WQ   32
#define NIT  (SEQ / BN)
#define PST  72          // prep/fallback LDS row stride (64 + 8 pad)

// async 16B global -> LDS (lds dest = wave-uniform base + lane*16)
#define GLDS16(gp, lp) __builtin_amdgcn_global_load_lds( \
    (const __attribute__((address_space(1))) uint32_t*)(gp), \
    (__attribute__((address_space(3))) uint32_t*)(lp), 16, 0, 0)

// pack two f32 -> u32 of 2 bf16 (compiler emits v_cvt_pk_bf16_f32)
static __device__ __forceinline__ unsigned pkbf(float a, float b) {
    union { bf16x2 h; unsigned u; } t;
    t.h[0] = (bf16_t)a; t.h[1] = (bf16_t)b;
    return t.u;
}

// ---------------- fused pre-pass: K scale+cvt, V transpose (one launch) ----------------
__global__ __launch_bounds__(256)
void prep_kv(const float* __restrict__ Kg, const float* __restrict__ SFg,
             bf16_t* __restrict__ Kb, const float* __restrict__ Vg,
             bf16_t* __restrict__ Vt)
{
    __shared__ __align__(16) bf16_t lt[HD * PST];
    const int tid = threadIdx.x;
    if (blockIdx.x < 8192) {
        const float c2 = 1.4426950408889634f / SFg[0];
        size_t idx = (size_t)blockIdx.x * 256 + tid;   // *8 elems each
        const float* src = Kg + idx * 8;
        f32x4 a = *(const f32x4*)src;
        f32x4 b = *(const f32x4*)(src + 4);
        bf16x8 o;
        o[0] = (bf16_t)(a[0] * c2); o[1] = (bf16_t)(a[1] * c2);
        o[2] = (bf16_t)(a[2] * c2); o[3] = (bf16_t)(a[3] * c2);
        o[4] = (bf16_t)(b[0] * c2); o[5] = (bf16_t)(b[1] * c2);
        o[6] = (bf16_t)(b[2] * c2); o[7] = (bf16_t)(b[3] * c2);
        *(bf16x8*)(Kb + idx * 8) = o;
        return;
    }
    const int vb    = blockIdx.x - 8192;
    const int batch = vb >> 5;
    const int kv0   = (vb & 31) * 64;
    const size_t bo = (size_t)batch * SEQ * HD;
#pragma unroll
    for (int s = 0; s < 4; ++s) {
        int p  = s * 256 + tid;
        int c4 = p & 31;
        int r  = (p >> 5) * 2;
        const float* vp = Vg + bo + (size_t)(kv0 + r) * HD + c4 * 4;
        f32x4 v0 = *(const f32x4*)vp;
        f32x4 v1 = *(const f32x4*)(vp + HD);
        const int swz = (c4 & 7) << 3;
#pragma unroll
        for (int u = 0; u < 4; ++u) {
            int d = c4 * 4 + u;
            bf16x2 w; w[0] = (bf16_t)v0[u]; w[1] = (bf16_t)v1[u];
            *(bf16x2*)&lt[d * PST + (r ^ swz)] = w;
        }
    }
    __syncthreads();
#pragma unroll
    for (int q = 0; q < 4; ++q) {
        int idx = q * 256 + tid;
        int d   = idx >> 3;          // 0..127
        int c8  = idx & 7;           // 0..7
        int cc  = (c8 * 8) ^ (((d >> 2) & 7) << 3);
        bf16x8 w = *(const bf16x8*)&lt[d * PST + cc];
        *(bf16x8*)(Vt + ((size_t)batch * HD + d) * SEQ + kv0 + c8 * 8) = w;
    }
}

// ---------------- main flash-attention kernel (workspace path) ----------------
// v6: concurrency fix. v5 (203us) showed 2 waves/SIMD, MFMA 27%, nothing
// saturated -> dependency-stall bound, and 1024 blocks @2/CU = 2 serial rounds.
// v6 keeps the v5 per-wave algorithm + barrier structure EXACTLY, but:
//  - 512-thread blocks (8 waves), BMW=256 q rows: K/V staging shared by 8 waves
//    (2+2 global_load_lds per thread instead of 4+4), LDS still 64 KB/block
//    -> 2 blocks/CU = 16 waves/CU = 4 waves/SIMD (2x TLP).
//  - grid 512 blocks = exactly 2/CU: single dispatch round (serial depth halves).
//  - __launch_bounds__(512,4) caps VGPR at 128 (v5 measured 116).
// Swizzle keys (row&15 for K, d&7 for V) are invariant to the new 32/64-row
// stage grouping (mod-16/mod-8 arithmetic) -> read algebra unchanged.

#define STAGE(KB_, VB_, T_) do {                                              \
    const size_t ko_ = (size_t)(T_) * BN * HD;                                \
    GLDS16(kbase + ko_,                        &KB_[tid * 8]);                \
    GLDS16(kbase + ko_ + 32 * HD,              &KB_[tid * 8 + 4096]);         \
    GLDS16(vbase + (size_t)(T_) * BN,          &VB_[tid * 8]);                \
    GLDS16(vbase + (size_t)(T_) * BN + 64 * SEQ, &VB_[tid * 8 + 4096]);       \
} while (0)

#define KV_BODY(KC_, VC_, KN_, VN_, IT_) do {                                 \
    if ((IT_) + 1 < NIT) STAGE(KN_, VN_, (IT_) + 1);                          \
    /* ---- QK^T: S^T[kv][q], A = K rows, B = Q; 2 kv-tiles x 8 k-steps ---- */ \
    f32x16 st0 = {}, st1 = {};                                                \
    __builtin_amdgcn_s_setprio(1);                                            \
    _Pragma("unroll")                                                         \
    for (int sp = 0; sp < 8; ++sp) {                                          \
        bf16x8 kf0 = *(const bf16x8*)&KC_[ q5        * HD + (((sp << 1) + hi) ^ swzk) * 8 ]; \
        bf16x8 kf1 = *(const bf16x8*)&KC_[ (q5 + 32) * HD + (((sp << 1) + hi) ^ swzk) * 8 ]; \
        st0 = __builtin_amdgcn_mfma_f32_32x32x16_bf16(kf0, qf[sp], st0, 0, 0, 0); \
        st1 = __builtin_amdgcn_mfma_f32_32x32x16_bf16(kf1, qf[sp], st1, 0, 0, 0); \
    }                                                                         \
    __builtin_amdgcn_s_setprio(0);                                            \
    /* ---- P = exp2(s), row-sums, pack + cross-half exchange -> pa[4] ---- */\
    bf16x8 pa[4];                                                             \
    _Pragma("unroll")                                                         \
    for (int mt = 0; mt < 2; ++mt) {                                          \
        float p[16];                                                          \
        _Pragma("unroll")                                                     \
        for (int r = 0; r < 16; ++r) {                                        \
            p[r] = __builtin_exp2f(mt ? st1[r] : st0[r]);                     \
            ssp[r & 3] += p[r];                                               \
        }                                                                     \
        unsigned uq[4][2];                                                    \
        _Pragma("unroll")                                                     \
        for (int c = 0; c < 4; ++c) {                                         \
            uq[c][0] = pkbf(p[4*c],     p[4*c + 1]);                          \
            uq[c][1] = pkbf(p[4*c + 2], p[4*c + 3]);                          \
        }                                                                     \
        _Pragma("unroll")                                                     \
        for (int ks = 0; ks < 2; ++ks) {                                      \
            unsigned w0, w1, w2, w3;                                          \
            {                                                                 \
                unsigned xlo = uq[2*ks][0], xhi = uq[2*ks + 1][0];            \
                unsigned snd = hi ? xlo : xhi;                                \
                unsigned rcv = (unsigned)__shfl_xor((int)snd, 32);            \
                w0 = hi ? rcv : xlo;                                          \
                w2 = hi ? xhi : rcv;                                          \
            }                                                                 \
            {                                                                 \
                unsigned xlo = uq[2*ks][1], xhi = uq[2*ks + 1][1];            \
                unsigned snd = hi ? xlo : xhi;                                \
                unsigned rcv = (unsigned)__shfl_xor((int)snd, 32);            \
                w1 = hi ? rcv : xlo;                                          \
                w3 = hi ? xhi : rcv;                                          \
            }                                                                 \
            union { unsigned u4[4]; bf16x8 v; } pu;                           \
            pu.u4[0] = w0; pu.u4[1] = w1; pu.u4[2] = w2; pu.u4[3] = w3;       \
            pa[mt * 2 + ks] = pu.v;                                           \
        }                                                                     \
    }                                                                         \
    /* ---- PV: A = P (regs), B = V^T from LDS; 4 d-tiles x 4 k-steps ---- */ \
    __builtin_amdgcn_s_setprio(1);                                            \
    _Pragma("unroll")                                                         \
    for (int dn = 0; dn < 4; ++dn) {                                          \
        _Pragma("unroll")                                                     \
        for (int kq = 0; kq < 4; ++kq) {                                      \
            bf16x8 vf = *(const bf16x8*)&VC_[ (dn * 32 + q5) * BN + (((kq << 1) + hi) ^ swzv) * 8 ]; \
            acc[dn] = __builtin_amdgcn_mfma_f32_32x32x16_bf16(pa[kq], vf, acc[dn], 0, 0, 0); \
        }                                                                     \
    }                                                                         \
    __builtin_amdgcn_s_setprio(0);                                            \
    __syncthreads();   /* drains vmcnt: next tiles staged + all waves done reading */ \
} while (0)

__global__ __launch_bounds__(512, 4)
void fattn_ws(const float* __restrict__ Qg, const bf16_t* __restrict__ Kb,
              const bf16_t* __restrict__ Vtg, float* __restrict__ Og)
{
    __shared__ __align__(16) bf16_t kp0[BN * HD];     // 16384 B
    __shared__ __align__(16) bf16_t kp1[BN * HD];     // 16384 B
    __shared__ __align__(16) bf16_t vt0[HD * BN];     // 16384 B
    __shared__ __align__(16) bf16_t vt1[HD * BN];     // 16384 B
    // total 64 KB -> 2 blocks/CU (16 waves/CU, 4 waves/SIMD)

    const int tid  = threadIdx.x;
    const int wave = tid >> 6;      // 0..7
    const int lane = tid & 63;
    const int q5   = lane & 31;     // q within wave tile / kv row / d row
    const int hi   = lane >> 5;     // k-half select for all 32x32x16 fragments
    const int swzk = lane & 15;     // K LDS chunk XOR key (= row&15)
    const int swzv = lane & 7;      // V LDS chunk XOR key (= d&7)

    const int blk   = blockIdx.x;
    const int x     = blk & 7;
    const int ii    = blk >> 3;     // 0..63
    const int batch = x * 8 + (ii >> 3);
    const int qt    = ii & 7;

    const size_t bo    = (size_t)batch * SEQ * HD;
    const int    qbase = qt * BMW + wave * WQ;

    // Q fragments: lane holds Q[qbase+q5][sp*16 + hi*8 .. +8) for sp=0..7
    bf16x8 qf[8];
    {
        const float* qp = Qg + bo + (size_t)(qbase + q5) * HD + hi * 8;
#pragma unroll
        for (int sp = 0; sp < 8; ++sp) {
            f32x4 u0 = *(const f32x4*)(qp + sp * 16);
            f32x4 u1 = *(const f32x4*)(qp + sp * 16 + 4);
            bf16x8 f;
            f[0] = (bf16_t)u0[0]; f[1] = (bf16_t)u0[1];
            f[2] = (bf16_t)u0[2]; f[3] = (bf16_t)u0[3];
            f[4] = (bf16_t)u1[0]; f[5] = (bf16_t)u1[1];
            f[6] = (bf16_t)u1[2]; f[7] = (bf16_t)u1[3];
            qf[sp] = f;
        }
    }

    f32x16 acc[4];
#pragma unroll
    for (int dn = 0; dn < 4; ++dn) acc[dn] = (f32x16){};
    float ssp[4] = {0.f, 0.f, 0.f, 0.f};

    // staging address components (512 threads: K rows in 32-row groups,
    // Vt rows in 64-row groups; swizzle keys match read side mod 16 / mod 8)
    const int kr  = tid >> 4;               // 0..31, K row
    const int kcg = (tid & 15) ^ (kr & 15); // swizzled global chunk
    const bf16_t* kbase = Kb + (size_t)batch * SEQ * HD + (size_t)kr * HD + kcg * 8;
    const int vr  = tid >> 3;               // 0..63, Vt row
    const int vcg = (tid & 7) ^ (vr & 7);   // swizzled global chunk
    const bf16_t* vbase = Vtg + ((size_t)batch * HD + vr) * SEQ + vcg * 8;

    // prologue: tile 0 -> buffer 0 (one-time exposed staging)
    STAGE(kp0, vt0, 0);
    __syncthreads();

    for (int it = 0; it < NIT; it += 2) {
        KV_BODY(kp0, vt0, kp1, vt1, it);
        KV_BODY(kp1, vt1, kp0, vt0, it + 1);
    }

    // ---- epilogue: reduce l across the two lane-halves, normalize, store ----
    float tot = (ssp[0] + ssp[1]) + (ssp[2] + ssp[3]);
    tot += __shfl_xor(tot, 32);
    const float linv = 1.0f / tot;
#pragma unroll
    for (int r = 0; r < 16; ++r) {
        const int qrow = (r & 3) + 8 * (r >> 2) + 4 * hi;
        const float li = __shfl(linv, qrow);
#pragma unroll
        for (int dn = 0; dn < 4; ++dn)
            Og[bo + (size_t)(qbase + qrow) * HD + dn * 32 + q5] = acc[dn][r] * li;
    }
}

// ---------------- fallback (round-1 kernel, verbatim): used if ws too small ----------------
#define KST  136
#define VST  72

__global__ __launch_bounds__(256, 2)
void fattn_fb(const float* __restrict__ Qg, const float* __restrict__ Kg,
              const float* __restrict__ Vg, const float* __restrict__ SFg,
              float* __restrict__ Og)
{
    __shared__ bf16_t kl[BN * KST];
    __shared__ bf16_t vl[HD * VST];
    __shared__ bf16_t pl[4 * WQ * PST];

    const int tid  = threadIdx.x;
    const int wave = tid >> 6;
    const int lane = tid & 63;
    const int col  = lane & 15;
    const int qd   = lane >> 4;

    const int blk   = blockIdx.x;
    const int x     = blk & 7;
    const int i     = blk >> 3;
    const int batch = x * 8 + (i >> 4);
    const int qt    = i & 15;

    const float c2 = 1.4426950408889634f / SFg[0];
    const size_t bo    = (size_t)batch * SEQ * HD;
    const int    qbase = qt * BM + wave * WQ;

    bf16x8 qf[2][4];
#pragma unroll
    for (int nt = 0; nt < 2; ++nt) {
        const float* qrow = Qg + bo + (size_t)(qbase + nt * 16 + col) * HD + qd * 8;
#pragma unroll
        for (int kc = 0; kc < 4; ++kc) {
            f32x4 u0 = *(const f32x4*)(qrow + kc * 32);
            f32x4 u1 = *(const f32x4*)(qrow + kc * 32 + 4);
            bf16x8 f;
            f[0] = (bf16_t)u0[0]; f[1] = (bf16_t)u0[1];
            f[2] = (bf16_t)u0[2]; f[3] = (bf16_t)u0[3];
            f[4] = (bf16_t)u1[0]; f[5] = (bf16_t)u1[1];
            f[6] = (bf16_t)u1[2]; f[7] = (bf16_t)u1[3];
            qf[nt][kc] = f;
        }
    }

    f32x4 acc[2][8];
#pragma unroll
    for (int a = 0; a < 2; ++a)
#pragma unroll
        for (int n = 0; n < 8; ++n)
            acc[a][n] = (f32x4){0.f, 0.f, 0.f, 0.f};

    float m2[2]   = {-INFINITY, -INFINITY};
    float lsum[2] = {0.f, 0.f};

    for (int it = 0; it < NIT; ++it) {
        const size_t kvo = bo + (size_t)(it * BN) * HD;
        __syncthreads();
#pragma unroll
        for (int s = 0; s < 8; ++s) {
            int idx = s * 256 + tid;
            int r   = idx >> 5;
            int c4  = idx & 31;
            f32x4 v = *(const f32x4*)(Kg + kvo + (size_t)r * HD + c4 * 4);
            bf16x4 b;
            b[0] = (bf16_t)v[0]; b[1] = (bf16_t)v[1];
            b[2] = (bf16_t)v[2]; b[3] = (bf16_t)v[3];
            *(bf16x4*)&kl[r * KST + c4 * 4] = b;
        }
#pragma unroll
        for (int s = 0; s < 4; ++s) {
            int p  = s * 256 + tid;
            int c4 = p & 31;
            int r  = (p >> 5) * 2;
            const float* vp = Vg + kvo + (size_t)r * HD + c4 * 4;
            f32x4 v0 = *(const f32x4*)vp;
            f32x4 v1 = *(const f32x4*)(vp + HD);
            const int swz = (c4 & 7) << 3;
#pragma unroll
            for (int u = 0; u < 4; ++u) {
                int d = c4 * 4 + u;
                bf16x2 w;
                w[0] = (bf16_t)v0[u];
                w[1] = (bf16_t)v1[u];
                *(bf16x2*)&vl[d * VST + (r ^ swz)] = w;
            }
        }
        __syncthreads();

        f32x4 st[4][2];
#pragma unroll
        for (int mt = 0; mt < 4; ++mt)
#pragma unroll
            for (int nt = 0; nt < 2; ++nt)
                st[mt][nt] = (f32x4){0.f, 0.f, 0.f, 0.f};
#pragma unroll
        for (int mt = 0; mt < 4; ++mt) {
            const bf16_t* kr = &kl[(mt * 16 + col) * KST + qd * 8];
            bf16x8 kf[4];
#pragma unroll
            for (int kc = 0; kc < 4; ++kc)
                kf[kc] = *(const bf16x8*)(kr + kc * 32);
#pragma unroll
            for (int kc = 0; kc < 4; ++kc) {
                st[mt][0] = __builtin_amdgcn_mfma_f32_16x16x32_bf16(kf[kc], qf[0][kc], st[mt][0], 0, 0, 0);
                st[mt][1] = __builtin_amdgcn_mfma_f32_16x16x32_bf16(kf[kc], qf[1][kc], st[mt][1], 0, 0, 0);
            }
        }

        float alpha[2];
#pragma unroll
        for (int nt = 0; nt < 2; ++nt) {
            float mx = st[0][nt][0];
#pragma unroll
            for (int mt = 0; mt < 4; ++mt)
#pragma unroll
                for (int rg = 0; rg < 4; ++rg)
                    mx = fmaxf(mx, st[mt][nt][rg]);
            mx *= c2;
            mx = fmaxf(mx, __shfl_xor(mx, 16));
            mx = fmaxf(mx, __shfl_xor(mx, 32));
            const float mnew = fmaxf(m2[nt], mx);
            alpha[nt] = exp2f(m2[nt] - mnew);
            m2[nt]    = mnew;
            float ss = 0.f;
#pragma unroll
            for (int mt = 0; mt < 4; ++mt) {
                bf16x4 pb;
#pragma unroll
                for (int rg = 0; rg < 4; ++rg) {
                    float pv = exp2f(fmaf(st[mt][nt][rg], c2, -mnew));
                    ss += pv;
                    pb[rg] = (bf16_t)pv;
                }
                *(bf16x4*)&pl[(wave * WQ + nt * 16 + col) * PST + mt * 16 + qd * 4] = pb;
            }
            ss += __shfl_xor(ss, 16);
            ss += __shfl_xor(ss, 32);
            lsum[nt] = lsum[nt] * alpha[nt] + ss;
        }

        asm volatile("s_waitcnt lgkmcnt(0)" ::: "memory");

        float arow[2][4];
#pragma unroll
        for (int a = 0; a < 2; ++a)
#pragma unroll
            for (int rg = 0; rg < 4; ++rg)
                arow[a][rg] = __shfl(alpha[a], qd * 4 + rg);
#pragma unroll
        for (int a = 0; a < 2; ++a)
#pragma unroll
            for (int n = 0; n < 8; ++n)
#pragma unroll
                for (int rg = 0; rg < 4; ++rg)
                    acc[a][n][rg] *= arow[a][rg];

        bf16x8 pf[2][2];
#pragma unroll
        for (int a = 0; a < 2; ++a)
#pragma unroll
            for (int kc = 0; kc < 2; ++kc)
                pf[a][kc] = *(const bf16x8*)&pl[(wave * WQ + a * 16 + col) * PST + kc * 32 + qd * 8];
#pragma unroll
        for (int n = 0; n < 8; ++n) {
            const int d   = n * 16 + col;
            const int swz = ((d >> 2) & 7) << 3;
#pragma unroll
            for (int kc = 0; kc < 2; ++kc) {
                bf16x8 vf = *(const bf16x8*)&vl[d * VST + ((kc * 32 + qd * 8) ^ swz)];
                acc[0][n] = __builtin_amdgcn_mfma_f32_16x16x32_bf16(pf[0][kc], vf, acc[0][n], 0, 0, 0);
                acc[1][n] = __builtin_amdgcn_mfma_f32_16x16x32_bf16(pf[1][kc], vf, acc[1][n], 0, 0, 0);
            }
        }
    }

#pragma unroll
    for (int a = 0; a < 2; ++a) {
        float linv[4];
#pragma unroll
        for (int rg = 0; rg < 4; ++rg)
            linv[rg] = 1.0f / __shfl(lsum[a], qd * 4 + rg);
#pragma unroll
        for (int n = 0; n < 8; ++n)
#pragma unroll
            for (int rg = 0; rg < 4; ++rg) {
                int qrow = qbase + a * 16 + qd * 4 + rg;
                Og[bo + (size_t)qrow * HD + n * 16 + col] = acc[a][n][rg] * linv[rg];
            }
    }
}

extern "C" void kernel_launch(void* const* d_in, const int* in_sizes, int n_in,
                              void* d_out, int out_size, void* d_ws, size_t ws_size,
                              hipStream_t stream)
{
    const float* Q  = (const float*)d_in[0];
    const float* K  = (const float*)d_in[1];
    const float* V  = (const float*)d_in[2];
    const float* SF = (const float*)d_in[3];
    float* O = (float*)d_out;

    const size_t need = (size_t)2 * NB * SEQ * HD * sizeof(bf16_t) * 2;  // Kb + Vt = 64 MB
    if (ws_size >= need) {
        bf16_t* Kb = (bf16_t*)d_ws;
        bf16_t* Vt = Kb + (size_t)NB * SEQ * HD;
        prep_kv<<<dim3(8192 + 2048), dim3(256), 0, stream>>>(K, SF, Kb, V, Vt);
        fattn_ws<<<dim3(NB * (SEQ / BMW)), dim3(512), 0, stream>>>(Q, Kb, Vt, O);
    } else {
        fattn_fb<<<dim3(NB * (SEQ / BM)), dim3(256), 0, stream>>>(Q, K, V, SF, O);
    }
}

// Round 13
// 366.762 us; speedup vs baseline: 1.6436x; 1.6436x over previous
//
#include <hip/hip_runtime.h>
#include <hip/hip_bf16.h>
#include <math.h>
#include <stdint.h>

typedef __bf16 bf16_t;
typedef __bf16 bf16x2 __attribute__((ext_vector_type(2)));
typedef __bf16 bf16x4 __attribute__((ext_vector_type(4)));
typedef __bf16 bf16x8 __attribute__((ext_vector_type(8)));
typedef float  f32x4  __attribute__((ext_vector_type(4)));
typedef float  f32x16 __attribute__((ext_vector_type(16)));

#define NB   64
#define SEQ  2048
#define HD   128
#define BM   128        // fallback kernel q-tile
#define BMW  256        // ws kernel q-tile (8 waves x 32)
#define BN   64
#define WQ   32
#define NIT  (SEQ / BN)
#define PST  72          // prep/fallback LDS row stride (64 + 8 pad)

// async 16B global -> LDS (lds dest = wave-uniform base + lane*16)
#define GLDS16(gp, lp) __builtin_amdgcn_global_load_lds( \
    (const __attribute__((address_space(1))) uint32_t*)(gp), \
    (__attribute__((address_space(3))) uint32_t*)(lp), 16, 0, 0)

// explicit drain before barriers: guarantees all async LDS-DMA and LDS ops
// are complete regardless of what waitcnt the compiler chooses to emit.
#define VMFENCE asm volatile("s_waitcnt vmcnt(0) lgkmcnt(0)" ::: "memory")

// pack two f32 -> u32 of 2 bf16 (compiler emits v_cvt_pk_bf16_f32)
static __device__ __forceinline__ unsigned pkbf(float a, float b) {
    union { bf16x2 h; unsigned u; } t;
    t.h[0] = (bf16_t)a; t.h[1] = (bf16_t)b;
    return t.u;
}

// ---------------- fused pre-pass: K scale+cvt, V transpose (one launch) ----------------
__global__ __launch_bounds__(256)
void prep_kv(const float* __restrict__ Kg, const float* __restrict__ SFg,
             bf16_t* __restrict__ Kb, const float* __restrict__ Vg,
             bf16_t* __restrict__ Vt)
{
    __shared__ __align__(16) bf16_t lt[HD * PST];
    const int tid = threadIdx.x;
    if (blockIdx.x < 8192) {
        const float c2 = 1.4426950408889634f / SFg[0];
        size_t idx = (size_t)blockIdx.x * 256 + tid;   // *8 elems each
        const float* src = Kg + idx * 8;
        f32x4 a = *(const f32x4*)src;
        f32x4 b = *(const f32x4*)(src + 4);
        bf16x8 o;
        o[0] = (bf16_t)(a[0] * c2); o[1] = (bf16_t)(a[1] * c2);
        o[2] = (bf16_t)(a[2] * c2); o[3] = (bf16_t)(a[3] * c2);
        o[4] = (bf16_t)(b[0] * c2); o[5] = (bf16_t)(b[1] * c2);
        o[6] = (bf16_t)(b[2] * c2); o[7] = (bf16_t)(b[3] * c2);
        *(bf16x8*)(Kb + idx * 8) = o;
        return;
    }
    const int vb    = blockIdx.x - 8192;
    const int batch = vb >> 5;
    const int kv0   = (vb & 31) * 64;
    const size_t bo = (size_t)batch * SEQ * HD;
#pragma unroll
    for (int s = 0; s < 4; ++s) {
        int p  = s * 256 + tid;
        int c4 = p & 31;
        int r  = (p >> 5) * 2;
        const float* vp = Vg + bo + (size_t)(kv0 + r) * HD + c4 * 4;
        f32x4 v0 = *(const f32x4*)vp;
        f32x4 v1 = *(const f32x4*)(vp + HD);
        const int swz = (c4 & 7) << 3;
#pragma unroll
        for (int u = 0; u < 4; ++u) {
            int d = c4 * 4 + u;
            bf16x2 w; w[0] = (bf16_t)v0[u]; w[1] = (bf16_t)v1[u];
            *(bf16x2*)&lt[d * PST + (r ^ swz)] = w;
        }
    }
    __syncthreads();
#pragma unroll
    for (int q = 0; q < 4; ++q) {
        int idx = q * 256 + tid;
        int d   = idx >> 3;          // 0..127
        int c8  = idx & 7;           // 0..7
        int cc  = (c8 * 8) ^ (((d >> 2) & 7) << 3);
        bf16x8 w = *(const bf16x8*)&lt[d * PST + cc];
        *(bf16x8*)(Vt + ((size_t)batch * HD + d) * SEQ + kv0 + c8 * 8) = w;
    }
}

// ---------------- main flash-attention kernel (workspace path) ----------------
// v7b = v7 + explicit vmcnt/lgkmcnt fences before every barrier.
// R10: v7 passed pre-timing correctness but ONE graph replay corrupted the
// output (post-timing absmax 0.134) -> intermittent race. The only in-kernel
// actionable suspect is the implicit vmcnt(0) drain the compiler is supposed
// to emit before s_barrier (documented behavior, not an arch guarantee, and
// sensitive to regalloc/scheduling changes). VMFENCE makes it explicit; zero
// cost if redundant.
// Structure (unchanged from v7):
//  - 8-wave 512-thread blocks, BMW=256 q rows, K/V staging shared by 8 waves.
//  - LDS 64 KB, __launch_bounds__(512,2) -> 2 blocks/CU, VGPR cap 128 (R8:
//    (512,4) meant 4 BLOCKS/CU -> cap 64 -> spill disaster).
//  - grid 512 blocks = exactly 2/CU: single dispatch round.
//  - v5 per-wave algorithm: 32x32x16 MFMA, in-register P via shfl_xor(32).

#define STAGE(KB_, VB_, T_) do {                                              \
    const size_t ko_ = (size_t)(T_) * BN * HD;                                \
    GLDS16(kbase + ko_,                        &KB_[tid * 8]);                \
    GLDS16(kbase + ko_ + 32 * HD,              &KB_[tid * 8 + 4096]);         \
    GLDS16(vbase + (size_t)(T_) * BN,          &VB_[tid * 8]);                \
    GLDS16(vbase + (size_t)(T_) * BN + 64 * SEQ, &VB_[tid * 8 + 4096]);       \
} while (0)

#define KV_BODY(KC_, VC_, KN_, VN_, IT_) do {                                 \
    if ((IT_) + 1 < NIT) STAGE(KN_, VN_, (IT_) + 1);                          \
    /* ---- QK^T: S^T[kv][q], A = K rows, B = Q; 2 kv-tiles x 8 k-steps ---- */ \
    f32x16 st0 = {}, st1 = {};                                                \
    __builtin_amdgcn_s_setprio(1);                                            \
    _Pragma("unroll")                                                         \
    for (int sp = 0; sp < 8; ++sp) {                                          \
        bf16x8 kf0 = *(const bf16x8*)&KC_[ q5        * HD + (((sp << 1) + hi) ^ swzk) * 8 ]; \
        bf16x8 kf1 = *(const bf16x8*)&KC_[ (q5 + 32) * HD + (((sp << 1) + hi) ^ swzk) * 8 ]; \
        st0 = __builtin_amdgcn_mfma_f32_32x32x16_bf16(kf0, qf[sp], st0, 0, 0, 0); \
        st1 = __builtin_amdgcn_mfma_f32_32x32x16_bf16(kf1, qf[sp], st1, 0, 0, 0); \
    }                                                                         \
    __builtin_amdgcn_s_setprio(0);                                            \
    /* ---- P = exp2(s), row-sums, pack + cross-half exchange -> pa[4] ---- */\
    bf16x8 pa[4];                                                             \
    _Pragma("unroll")                                                         \
    for (int mt = 0; mt < 2; ++mt) {                                          \
        float p[16];                                                          \
        _Pragma("unroll")                                                     \
        for (int r = 0; r < 16; ++r) {                                        \
            p[r] = __builtin_exp2f(mt ? st1[r] : st0[r]);                     \
            ssp[r & 3] += p[r];                                               \
        }                                                                     \
        unsigned uq[4][2];                                                    \
        _Pragma("unroll")                                                     \
        for (int c = 0; c < 4; ++c) {                                         \
            uq[c][0] = pkbf(p[4*c],     p[4*c + 1]);                          \
            uq[c][1] = pkbf(p[4*c + 2], p[4*c + 3]);                          \
        }                                                                     \
        _Pragma("unroll")                                                     \
        for (int ks = 0; ks < 2; ++ks) {                                      \
            unsigned w0, w1, w2, w3;                                          \
            {                                                                 \
                unsigned xlo = uq[2*ks][0], xhi = uq[2*ks + 1][0];            \
                unsigned snd = hi ? xlo : xhi;                                \
                unsigned rcv = (unsigned)__shfl_xor((int)snd, 32);            \
                w0 = hi ? rcv : xlo;                                          \
                w2 = hi ? xhi : rcv;                                          \
            }                                                                 \
            {                                                                 \
                unsigned xlo = uq[2*ks][1], xhi = uq[2*ks + 1][1];            \
                unsigned snd = hi ? xlo : xhi;                                \
                unsigned rcv = (unsigned)__shfl_xor((int)snd, 32);            \
                w1 = hi ? rcv : xlo;                                          \
                w3 = hi ? xhi : rcv;                                          \
            }                                                                 \
            union { unsigned u4[4]; bf16x8 v; } pu;                           \
            pu.u4[0] = w0; pu.u4[1] = w1; pu.u4[2] = w2; pu.u4[3] = w3;       \
            pa[mt * 2 + ks] = pu.v;                                           \
        }                                                                     \
    }                                                                         \
    /* ---- PV: A = P (regs), B = V^T from LDS; 4 d-tiles x 4 k-steps ---- */ \
    __builtin_amdgcn_s_setprio(1);                                            \
    _Pragma("unroll")                                                         \
    for (int dn = 0; dn < 4; ++dn) {                                          \
        _Pragma("unroll")                                                     \
        for (int kq = 0; kq < 4; ++kq) {                                      \
            bf16x8 vf = *(const bf16x8*)&VC_[ (dn * 32 + q5) * BN + (((kq << 1) + hi) ^ swzv) * 8 ]; \
            acc[dn] = __builtin_amdgcn_mfma_f32_32x32x16_bf16(pa[kq], vf, acc[dn], 0, 0, 0); \
        }                                                                     \
    }                                                                         \
    __builtin_amdgcn_s_setprio(0);                                            \
    VMFENCE;           /* explicit: all DMA landed + all LDS reads complete */ \
    __syncthreads();   /* next tiles staged + all waves done reading */       \
} while (0)

__global__ __launch_bounds__(512, 2)
void fattn_ws(const float* __restrict__ Qg, const bf16_t* __restrict__ Kb,
              const bf16_t* __restrict__ Vtg, float* __restrict__ Og)
{
    __shared__ __align__(16) bf16_t kp0[BN * HD];     // 16384 B
    __shared__ __align__(16) bf16_t kp1[BN * HD];     // 16384 B
    __shared__ __align__(16) bf16_t vt0[HD * BN];     // 16384 B
    __shared__ __align__(16) bf16_t vt1[HD * BN];     // 16384 B
    // total 64 KB -> 2 blocks/CU (16 waves/CU, 4 waves/SIMD); VGPR cap 128

    const int tid  = threadIdx.x;
    const int wave = tid >> 6;      // 0..7
    const int lane = tid & 63;
    const int q5   = lane & 31;     // q within wave tile / kv row / d row
    const int hi   = lane >> 5;     // k-half select for all 32x32x16 fragments
    const int swzk = lane & 15;     // K LDS chunk XOR key (= row&15)
    const int swzv = lane & 7;      // V LDS chunk XOR key (= d&7)

    const int blk   = blockIdx.x;
    const int x     = blk & 7;
    const int ii    = blk >> 3;     // 0..63
    const int batch = x * 8 + (ii >> 3);
    const int qt    = ii & 7;

    const size_t bo    = (size_t)batch * SEQ * HD;
    const int    qbase = qt * BMW + wave * WQ;

    // Q fragments: lane holds Q[qbase+q5][sp*16 + hi*8 .. +8) for sp=0..7
    bf16x8 qf[8];
    {
        const float* qp = Qg + bo + (size_t)(qbase + q5) * HD + hi * 8;
#pragma unroll
        for (int sp = 0; sp < 8; ++sp) {
            f32x4 u0 = *(const f32x4*)(qp + sp * 16);
            f32x4 u1 = *(const f32x4*)(qp + sp * 16 + 4);
            bf16x8 f;
            f[0] = (bf16_t)u0[0]; f[1] = (bf16_t)u0[1];
            f[2] = (bf16_t)u0[2]; f[3] = (bf16_t)u0[3];
            f[4] = (bf16_t)u1[0]; f[5] = (bf16_t)u1[1];
            f[6] = (bf16_t)u1[2]; f[7] = (bf16_t)u1[3];
            qf[sp] = f;
        }
    }

    f32x16 acc[4];
#pragma unroll
    for (int dn = 0; dn < 4; ++dn) acc[dn] = (f32x16){};
    float ssp[4] = {0.f, 0.f, 0.f, 0.f};

    // staging address components (512 threads: K rows in 32-row groups,
    // Vt rows in 64-row groups; swizzle keys match read side mod 16 / mod 8)
    const int kr  = tid >> 4;               // 0..31, K row
    const int kcg = (tid & 15) ^ (kr & 15); // swizzled global chunk
    const bf16_t* kbase = Kb + (size_t)batch * SEQ * HD + (size_t)kr * HD + kcg * 8;
    const int vr  = tid >> 3;               // 0..63, Vt row
    const int vcg = (tid & 7) ^ (vr & 7);   // swizzled global chunk
    const bf16_t* vbase = Vtg + ((size_t)batch * HD + vr) * SEQ + vcg * 8;

    // prologue: tile 0 -> buffer 0 (one-time exposed staging)
    STAGE(kp0, vt0, 0);
    VMFENCE;
    __syncthreads();

    for (int it = 0; it < NIT; it += 2) {
        KV_BODY(kp0, vt0, kp1, vt1, it);
        KV_BODY(kp1, vt1, kp0, vt0, it + 1);
    }

    // ---- epilogue: reduce l across the two lane-halves, normalize, store ----
    float tot = (ssp[0] + ssp[1]) + (ssp[2] + ssp[3]);
    tot += __shfl_xor(tot, 32);
    const float linv = 1.0f / tot;
#pragma unroll
    for (int r = 0; r < 16; ++r) {
        const int qrow = (r & 3) + 8 * (r >> 2) + 4 * hi;
        const float li = __shfl(linv, qrow);
#pragma unroll
        for (int dn = 0; dn < 4; ++dn)
            Og[bo + (size_t)(qbase + qrow) * HD + dn * 32 + q5] = acc[dn][r] * li;
    }
}

// ---------------- fallback (round-1 kernel, verbatim): used if ws too small ----------------
#define KST  136
#define VST  72

__global__ __launch_bounds__(256, 2)
void fattn_fb(const float* __restrict__ Qg, const float* __restrict__ Kg,
              const float* __restrict__ Vg, const float* __restrict__ SFg,
              float* __restrict__ Og)
{
    __shared__ bf16_t kl[BN * KST];
    __shared__ bf16_t vl[HD * VST];
    __shared__ bf16_t pl[4 * WQ * PST];

    const int tid  = threadIdx.x;
    const int wave = tid >> 6;
    const int lane = tid & 63;
    const int col  = lane & 15;
    const int qd   = lane >> 4;

    const int blk   = blockIdx.x;
    const int x     = blk & 7;
    const int i     = blk >> 3;
    const int batch = x * 8 + (i >> 4);
    const int qt    = i & 15;

    const float c2 = 1.4426950408889634f / SFg[0];
    const size_t bo    = (size_t)batch * SEQ * HD;
    const int    qbase = qt * BM + wave * WQ;

    bf16x8 qf[2][4];
#pragma unroll
    for (int nt = 0; nt < 2; ++nt) {
        const float* qrow = Qg + bo + (size_t)(qbase + nt * 16 + col) * HD + qd * 8;
#pragma unroll
        for (int kc = 0; kc < 4; ++kc) {
            f32x4 u0 = *(const f32x4*)(qrow + kc * 32);
            f32x4 u1 = *(const f32x4*)(qrow + kc * 32 + 4);
            bf16x8 f;
            f[0] = (bf16_t)u0[0]; f[1] = (bf16_t)u0[1];
            f[2] = (bf16_t)u0[2]; f[3] = (bf16_t)u0[3];
            f[4] = (bf16_t)u1[0]; f[5] = (bf16_t)u1[1];
            f[6] = (bf16_t)u1[2]; f[7] = (bf16_t)u1[3];
            qf[nt][kc] = f;
        }
    }

    f32x4 acc[2][8];
#pragma unroll
    for (int a = 0; a < 2; ++a)
#pragma unroll
        for (int n = 0; n < 8; ++n)
            acc[a][n] = (f32x4){0.f, 0.f, 0.f, 0.f};

    float m2[2]   = {-INFINITY, -INFINITY};
    float lsum[2] = {0.f, 0.f};

    for (int it = 0; it < NIT; ++it) {
        const size_t kvo = bo + (size_t)(it * BN) * HD;
        __syncthreads();
#pragma unroll
        for (int s = 0; s < 8; ++s) {
            int idx = s * 256 + tid;
            int r   = idx >> 5;
            int c4  = idx & 31;
            f32x4 v = *(const f32x4*)(Kg + kvo + (size_t)r * HD + c4 * 4);
            bf16x4 b;
            b[0] = (bf16_t)v[0]; b[1] = (bf16_t)v[1];
            b[2] = (bf16_t)v[2]; b[3] = (bf16_t)v[3];
            *(bf16x4*)&kl[r * KST + c4 * 4] = b;
        }
#pragma unroll
        for (int s = 0; s < 4; ++s) {
            int p  = s * 256 + tid;
            int c4 = p & 31;
            int r  = (p >> 5) * 2;
            const float* vp = Vg + kvo + (size_t)r * HD + c4 * 4;
            f32x4 v0 = *(const f32x4*)vp;
            f32x4 v1 = *(const f32x4*)(vp + HD);
            const int swz = (c4 & 7) << 3;
#pragma unroll
            for (int u = 0; u < 4; ++u) {
                int d = c4 * 4 + u;
                bf16x2 w;
                w[0] = (bf16_t)v0[u];
                w[1] = (bf16_t)v1[u];
                *(bf16x2*)&vl[d * VST + (r ^ swz)] = w;
            }
        }
        __syncthreads();

        f32x4 st[4][2];
#pragma unroll
        for (int mt = 0; mt < 4; ++mt)
#pragma unroll
            for (int nt = 0; nt < 2; ++nt)
                st[mt][nt] = (f32x4){0.f, 0.f, 0.f, 0.f};
#pragma unroll
        for (int mt = 0; mt < 4; ++mt) {
            const bf16_t* kr = &kl[(mt * 16 + col) * KST + qd * 8];
            bf16x8 kf[4];
#pragma unroll
            for (int kc = 0; kc < 4; ++kc)
                kf[kc] = *(const bf16x8*)(kr + kc * 32);
#pragma unroll
            for (int kc = 0; kc < 4; ++kc) {
                st[mt][0] = __builtin_amdgcn_mfma_f32_16x16x32_bf16(kf[kc], qf[0][kc], st[mt][0], 0, 0, 0);
                st[mt][1] = __builtin_amdgcn_mfma_f32_16x16x32_bf16(kf[kc], qf[1][kc], st[mt][1], 0, 0, 0);
            }
        }

        float alpha[2];
#pragma unroll
        for (int nt = 0; nt < 2; ++nt) {
            float mx = st[0][nt][0];
#pragma unroll
            for (int mt = 0; mt < 4; ++mt)
#pragma unroll
                for (int rg = 0; rg < 4; ++rg)
                    mx = fmaxf(mx, st[mt][nt][rg]);
            mx *= c2;
            mx = fmaxf(mx, __shfl_xor(mx, 16));
            mx = fmaxf(mx, __shfl_xor(mx, 32));
            const float mnew = fmaxf(m2[nt], mx);
            alpha[nt] = exp2f(m2[nt] - mnew);
            m2[nt]    = mnew;
            float ss = 0.f;
#pragma unroll
            for (int mt = 0; mt < 4; ++mt) {
                bf16x4 pb;
#pragma unroll
                for (int rg = 0; rg < 4; ++rg) {
                    float pv = exp2f(fmaf(st[mt][nt][rg], c2, -mnew));
                    ss += pv;
                    pb[rg] = (bf16_t)pv;
                }
                *(bf16x4*)&pl[(wave * WQ + nt * 16 + col) * PST + mt * 16 + qd * 4] = pb;
            }
            ss += __shfl_xor(ss, 16);
            ss += __shfl_xor(ss, 32);
            lsum[nt] = lsum[nt] * alpha[nt] + ss;
        }

        asm volatile("s_waitcnt lgkmcnt(0)" ::: "memory");

        float arow[2][4];
#pragma unroll
        for (int a = 0; a < 2; ++a)
#pragma unroll
            for (int rg = 0; rg < 4; ++rg)
                arow[a][rg] = __shfl(alpha[a], qd * 4 + rg);
#pragma unroll
        for (int a = 0; a < 2; ++a)
#pragma unroll
            for (int n = 0; n < 8; ++n)
#pragma unroll
                for (int rg = 0; rg < 4; ++rg)
                    acc[a][n][rg] *= arow[a][rg];

        bf16x8 pf[2][2];
#pragma unroll
        for (int a = 0; a < 2; ++a)
#pragma unroll
            for (int kc = 0; kc < 2; ++kc)
                pf[a][kc] = *(const bf16x8*)&pl[(wave * WQ + a * 16 + col) * PST + kc * 32 + qd * 8];
#pragma unroll
        for (int n = 0; n < 8; ++n) {
            const int d   = n * 16 + col;
            const int swz = ((d >> 2) & 7) << 3;
#pragma unroll
            for (int kc = 0; kc < 2; ++kc) {
                bf16x8 vf = *(const bf16x8*)&vl[d * VST + ((kc * 32 + qd * 8) ^ swz)];
                acc[0][n] = __builtin_amdgcn_mfma_f32_16x16x32_bf16(pf[0][kc], vf, acc[0][n], 0, 0, 0);
                acc[1][n] = __builtin_amdgcn_mfma_f32_16x16x32_bf16(pf[1][kc], vf, acc[1][n], 0, 0, 0);
            }
        }
    }

#pragma unroll
    for (int a = 0; a < 2; ++a) {
        float linv[4];
#pragma unroll
        for (int rg = 0; rg < 4; ++rg)
            linv[rg] = 1.0f / __shfl(lsum[a], qd * 4 + rg);
#pragma unroll
        for (int n = 0; n < 8; ++n)
#pragma unroll
            for (int rg = 0; rg < 4; ++rg) {
                int qrow = qbase + a * 16 + qd * 4 + rg;
                Og[bo + (size_t)qrow * HD + n * 16 + col] = acc[a][n][rg] * linv[rg];
            }
    }
}

extern "C" void kernel_launch(void* const* d_in, const int* in_sizes, int n_in,
                              void* d_out, int out_size, void* d_ws, size_t ws_size,
                              hipStream_t stream)
{
    const float* Q  = (const float*)d_in[0];
    const float* K  = (const float*)d_in[1];
    const float* V  = (const float*)d_in[2];
    const float* SF = (const float*)d_in[3];
    float* O = (float*)d_out;

    const size_t need = (size_t)2 * NB * SEQ * HD * sizeof(bf16_t) * 2;  // Kb + Vt (conservative)
    if (ws_size >= need) {
        bf16_t* Kb = (bf16_t*)d_ws;
        bf16_t* Vt = Kb + (size_t)NB * SEQ * HD;
        prep_kv<<<dim3(8192 + 2048), dim3(256), 0, stream>>>(K, SF, Kb, V, Vt);
        fattn_ws<<<dim3(NB * (SEQ / BMW)), dim3(512), 0, stream>>>(Q, Kb, Vt, O);
    } else {
        fattn_fb<<<dim3(NB * (SEQ / BM)), dim3(256), 0, stream>>>(Q, K, V, SF, O);
    }
}